// Round 1
// baseline (954.464 us; speedup 1.0000x reference)
//
#include <hip/hip_runtime.h>

#define DIM 64
#define KEEP_INV 2.0f
#define SCAN_B 1024

// ---------------- mask dtype detector ----------------
// jax bool arrays are 1 byte/elem; but if the harness widened to int32,
// element e's byte is at 4*e (little-endian). Detect by nonzero-byte density
// over the first 4KB: bool ~50%, int32 ~12.5%. Write stride (1 or 4) to flag.
__global__ void detect_mask_kernel(const unsigned char* __restrict__ m,
                                   int nbytes, int* __restrict__ flag) {
    __shared__ int cnt;
    if (threadIdx.x == 0) cnt = 0;
    __syncthreads();
    int c = 0;
    for (int i = threadIdx.x; i < nbytes; i += blockDim.x)
        c += (m[i] != 0) ? 1 : 0;
    atomicAdd(&cnt, c);
    __syncthreads();
    if (threadIdx.x == 0) *flag = (cnt * 16 > nbytes * 5) ? 1 : 4;
}

// ---------------- emb0 = concat(user_w, item_w); acc = 0.25*emb0 ----------
__global__ void init_kernel(const float* __restrict__ uw,
                            const float* __restrict__ iw,
                            float* __restrict__ embA, float* __restrict__ out,
                            int n_user_elems, int total_elems) {
    int i = blockIdx.x * blockDim.x + threadIdx.x;
    int gs = gridDim.x * blockDim.x;
    for (; i < total_elems; i += gs) {
        float v = (i < n_user_elems) ? uw[i] : iw[i - n_user_elems];
        embA[i] = v;
        out[i] = 0.25f * v;
    }
}

// ---------------- histogram of kept edges per row ----------------
__global__ void hist_kernel(const int* __restrict__ rows,
                            const unsigned char* __restrict__ mask,
                            const int* __restrict__ flag, int nnz,
                            int* __restrict__ counts) {
    int sm = *flag;
    int i = blockIdx.x * blockDim.x + threadIdx.x;
    if (i < nnz) {
        if (mask[(size_t)i * sm] != 0) atomicAdd(&counts[rows[i]], 1);
    }
}

// ---------------- 3-phase exclusive scan over n = N_NODES+1 ----------------
__global__ void scan1_kernel(const int* __restrict__ counts, int n,
                             int* __restrict__ incl, int* __restrict__ bsums) {
    __shared__ int s[SCAN_B];
    int t = threadIdx.x, b = blockIdx.x, i = b * SCAN_B + t;
    int v = (i < n) ? counts[i] : 0;
    s[t] = v;
    __syncthreads();
    for (int off = 1; off < SCAN_B; off <<= 1) {
        int x = (t >= off) ? s[t - off] : 0;
        __syncthreads();
        s[t] += x;
        __syncthreads();
    }
    if (i < n) incl[i] = s[t];
    if (t == SCAN_B - 1) bsums[b] = s[t];
}

__global__ void scan2_kernel(int* __restrict__ bsums, int nb) {
    __shared__ int s[SCAN_B];
    int t = threadIdx.x;
    int v = (t < nb) ? bsums[t] : 0;
    s[t] = v;
    __syncthreads();
    for (int off = 1; off < SCAN_B; off <<= 1) {
        int x = (t >= off) ? s[t - off] : 0;
        __syncthreads();
        s[t] += x;
        __syncthreads();
    }
    if (t < nb) bsums[t] = s[t] - v;  // exclusive
}

__global__ void scan3_kernel(const int* __restrict__ incl,
                             const int* __restrict__ counts,
                             const int* __restrict__ bsums, int n,
                             int* __restrict__ rowptr, int* __restrict__ cursor) {
    int t = threadIdx.x, b = blockIdx.x, i = b * SCAN_B + t;
    if (i < n) {
        int excl = incl[i] - counts[i] + bsums[b];
        rowptr[i] = excl;
        cursor[i] = excl;
    }
}

// ---------------- scatter kept edges into CSR ----------------
__global__ void scatter_kernel(const int* __restrict__ rows,
                               const int* __restrict__ cols,
                               const float* __restrict__ vals,
                               const unsigned char* __restrict__ mask,
                               const int* __restrict__ flag, int nnz,
                               int* __restrict__ cursor, int* __restrict__ scol,
                               float* __restrict__ sval) {
    int sm = *flag;
    int i = blockIdx.x * blockDim.x + threadIdx.x;
    if (i < nnz) {
        if (mask[(size_t)i * sm] != 0) {
            int r = rows[i];
            int p = atomicAdd(&cursor[r], 1);
            scol[p] = cols[i];
            sval[p] = vals[i] * KEEP_INV;
        }
    }
}

// ---------------- SpMM: one wave per row, lane = dim ----------------
__global__ void spmm_kernel(const int* __restrict__ rowptr,
                            const int* __restrict__ scol,
                            const float* __restrict__ sval,
                            const float* __restrict__ embA,
                            float* __restrict__ embB, float* __restrict__ out,
                            int nrows) {
    int wave = (int)((blockIdx.x * blockDim.x + threadIdx.x) >> 6);
    int lane = threadIdx.x & 63;
    if (wave >= nrows) return;
    int start = rowptr[wave];
    int end = rowptr[wave + 1];
    float s = 0.f;
    for (int e = start; e < end; ++e) {
        int c = scol[e];
        float v = sval[e];
        s += v * embA[(size_t)c * DIM + lane];
    }
    size_t o = (size_t)wave * DIM + lane;
    embB[o] = s;
    out[o] += 0.25f * s;
}

extern "C" void kernel_launch(void* const* d_in, const int* in_sizes, int n_in,
                              void* d_out, int out_size, void* d_ws, size_t ws_size,
                              hipStream_t stream) {
    const float* user_w = (const float*)d_in[0];
    const float* item_w = (const float*)d_in[1];
    const float* vals   = (const float*)d_in[2];
    const int*   rows   = (const int*)d_in[3];
    const int*   cols   = (const int*)d_in[4];
    const unsigned char* mask = (const unsigned char*)d_in[5];

    const int n_user = in_sizes[0] / DIM;
    const int n_item = in_sizes[1] / DIM;
    const int nnz    = in_sizes[2];
    const int n_nodes = n_user + n_item;
    const int n_elems = n_nodes * DIM;

    // ---- workspace layout ----
    char* ws = (char*)d_ws;
    size_t off = 0;
    auto alloc = [&](size_t bytes) {
        void* p = ws + off;
        off = (off + bytes + 255) & ~(size_t)255;
        return p;
    };
    int*   counts  = (int*)alloc((size_t)(n_nodes + 1) * 4);
    int*   rowptr  = (int*)alloc((size_t)(n_nodes + 1) * 4);
    int*   cursor  = (int*)alloc((size_t)(n_nodes + 1) * 4);
    int*   bsums   = (int*)alloc(SCAN_B * 4);
    int*   flag    = (int*)alloc(256);
    int*   scol    = (int*)alloc((size_t)nnz * 4);
    float* sval    = (float*)alloc((size_t)nnz * 4);
    float* embA    = (float*)alloc((size_t)n_elems * 4);
    float* embB    = (float*)alloc((size_t)n_elems * 4);
    float* outf    = (float*)d_out;

    // ---- mask dtype detect ----
    detect_mask_kernel<<<1, 256, 0, stream>>>(mask, 4096, flag);

    // ---- init emb0 + acc ----
    {
        int blocks = 2048;
        init_kernel<<<blocks, 256, 0, stream>>>(user_w, item_w, embA, outf,
                                                n_user * DIM, n_elems);
    }

    // ---- CSR build ----
    hipMemsetAsync(counts, 0, (size_t)(n_nodes + 1) * 4, stream);
    {
        int blocks = (nnz + 255) / 256;
        hist_kernel<<<blocks, 256, 0, stream>>>(rows, mask, flag, nnz, counts);
    }
    int n_scan = n_nodes + 1;
    int nb = (n_scan + SCAN_B - 1) / SCAN_B;
    scan1_kernel<<<nb, SCAN_B, 0, stream>>>(counts, n_scan, rowptr, bsums);
    scan2_kernel<<<1, SCAN_B, 0, stream>>>(bsums, nb);
    scan3_kernel<<<nb, SCAN_B, 0, stream>>>(rowptr, counts, bsums, n_scan,
                                            rowptr, cursor);
    {
        int blocks = (nnz + 255) / 256;
        scatter_kernel<<<blocks, 256, 0, stream>>>(rows, cols, vals, mask, flag,
                                                   nnz, cursor, scol, sval);
    }

    // ---- 3 SpMM layers (ping-pong embA/embB), acc += 0.25*layer ----
    {
        int blocks = (n_nodes * 64 + 255) / 256;
        spmm_kernel<<<blocks, 256, 0, stream>>>(rowptr, scol, sval, embA, embB,
                                                outf, n_nodes);
        spmm_kernel<<<blocks, 256, 0, stream>>>(rowptr, scol, sval, embB, embA,
                                                outf, n_nodes);
        spmm_kernel<<<blocks, 256, 0, stream>>>(rowptr, scol, sval, embA, embB,
                                                outf, n_nodes);
    }
}

// Round 2
// 562.135 us; speedup vs baseline: 1.6979x; 1.6979x over previous
//
#include <hip/hip_runtime.h>

#define DIM 64
#define KEEP_INV 2.0f
#define SCAN_B 1024

// ---------------- mask dtype detector ----------------
// jax bool arrays are 1 byte/elem; if widened to int32, element e's byte is
// at 4*e (LE). Detect by nonzero-byte density over first 4KB: bool ~50%,
// int32 ~12.5%. Write stride (1 or 4) to flag.
__global__ void detect_mask_kernel(const unsigned char* __restrict__ m,
                                   int nbytes, int* __restrict__ flag) {
    __shared__ int cnt;
    if (threadIdx.x == 0) cnt = 0;
    __syncthreads();
    int c = 0;
    for (int i = threadIdx.x; i < nbytes; i += blockDim.x)
        c += (m[i] != 0) ? 1 : 0;
    atomicAdd(&cnt, c);
    __syncthreads();
    if (threadIdx.x == 0) *flag = (cnt * 16 > nbytes * 5) ? 1 : 4;
}

// ---------------- emb0 = concat(user_w, item_w); acc = 0.25*emb0 ----------
__global__ void init_kernel(const float4* __restrict__ uw,
                            const float4* __restrict__ iw,
                            float4* __restrict__ embA, float4* __restrict__ out,
                            int n_user_v, int total_v) {
    int i = blockIdx.x * blockDim.x + threadIdx.x;
    int gs = gridDim.x * blockDim.x;
    for (; i < total_v; i += gs) {
        float4 v = (i < n_user_v) ? uw[i] : iw[i - n_user_v];
        embA[i] = v;
        float4 o;
        o.x = 0.25f * v.x; o.y = 0.25f * v.y;
        o.z = 0.25f * v.z; o.w = 0.25f * v.w;
        out[i] = o;
    }
}

// ---------------- histogram of kept edges per row ----------------
__global__ void hist_kernel(const int* __restrict__ rows,
                            const unsigned char* __restrict__ mask,
                            const int* __restrict__ flag, int nnz,
                            int* __restrict__ counts) {
    int sm = *flag;
    int i = blockIdx.x * blockDim.x + threadIdx.x;
    if (i < nnz) {
        if (mask[(size_t)i * sm] != 0) atomicAdd(&counts[rows[i]], 1);
    }
}

// ---------------- 3-phase exclusive scan over n = N_NODES+1 ----------------
__global__ void scan1_kernel(const int* __restrict__ counts, int n,
                             int* __restrict__ incl, int* __restrict__ bsums) {
    __shared__ int s[SCAN_B];
    int t = threadIdx.x, b = blockIdx.x, i = b * SCAN_B + t;
    int v = (i < n) ? counts[i] : 0;
    s[t] = v;
    __syncthreads();
    for (int off = 1; off < SCAN_B; off <<= 1) {
        int x = (t >= off) ? s[t - off] : 0;
        __syncthreads();
        s[t] += x;
        __syncthreads();
    }
    if (i < n) incl[i] = s[t];
    if (t == SCAN_B - 1) bsums[b] = s[t];
}

__global__ void scan2_kernel(int* __restrict__ bsums, int nb) {
    __shared__ int s[SCAN_B];
    int t = threadIdx.x;
    int v = (t < nb) ? bsums[t] : 0;
    s[t] = v;
    __syncthreads();
    for (int off = 1; off < SCAN_B; off <<= 1) {
        int x = (t >= off) ? s[t - off] : 0;
        __syncthreads();
        s[t] += x;
        __syncthreads();
    }
    if (t < nb) bsums[t] = s[t] - v;  // exclusive
}

__global__ void scan3_kernel(const int* __restrict__ incl,
                             const int* __restrict__ counts,
                             const int* __restrict__ bsums, int n,
                             int* __restrict__ rowptr, int* __restrict__ cursor) {
    int t = threadIdx.x, b = blockIdx.x, i = b * SCAN_B + t;
    if (i < n) {
        int excl = incl[i] - counts[i] + bsums[b];
        rowptr[i] = excl;
        cursor[i] = excl;
    }
}

// ---------------- scatter kept edges into CSR (packed int2) ----------------
__global__ void scatter_kernel(const int* __restrict__ rows,
                               const int* __restrict__ cols,
                               const float* __restrict__ vals,
                               const unsigned char* __restrict__ mask,
                               const int* __restrict__ flag, int nnz,
                               int* __restrict__ cursor,
                               int2* __restrict__ edges) {
    int sm = *flag;
    int i = blockIdx.x * blockDim.x + threadIdx.x;
    if (i < nnz) {
        if (mask[(size_t)i * sm] != 0) {
            int r = rows[i];
            int p = atomicAdd(&cursor[r], 1);
            int2 e;
            e.x = cols[i];
            e.y = __float_as_int(vals[i] * KEEP_INV);
            edges[p] = e;
        }
    }
}

// ---------------- SpMM: wave per row; 4x16-lane groups; float4 lanes -------
// 16 independent 256B gathers in flight per wave per iteration.
__global__ void __launch_bounds__(256) spmm_kernel(
        const int* __restrict__ rowptr,
        const int2* __restrict__ edges,
        const float4* __restrict__ embv,   // [n_nodes * 16] float4
        float4* __restrict__ embB,
        float4* __restrict__ out,
        int nrows) {
    int wid = blockIdx.x * (blockDim.x >> 6) + (threadIdx.x >> 6);
    if (wid >= nrows) return;
    int lane = threadIdx.x & 63;
    int grp = lane >> 4;    // 0..3 : edge slot within iteration
    int l16 = lane & 15;    // dim quarter: float4 index within row
    int start = rowptr[wid];
    int end = rowptr[wid + 1];

    float4 acc;
    acc.x = acc.y = acc.z = acc.w = 0.f;

    for (int e0 = start; e0 < end; e0 += 16) {
        int c[4];
        float v[4];
#pragma unroll
        for (int k = 0; k < 4; ++k) {
            int idx = e0 + grp + 4 * k;
            int cl = idx < end ? idx : end - 1;  // clamp; dup-address gathers coalesce
            int2 p = edges[cl];
            c[k] = p.x;
            v[k] = (idx < end) ? __int_as_float(p.y) : 0.f;
        }
        float4 g[4];
#pragma unroll
        for (int k = 0; k < 4; ++k)
            g[k] = embv[(size_t)c[k] * 16 + l16];
#pragma unroll
        for (int k = 0; k < 4; ++k) {
            acc.x += v[k] * g[k].x;
            acc.y += v[k] * g[k].y;
            acc.z += v[k] * g[k].z;
            acc.w += v[k] * g[k].w;
        }
    }

    // reduce across the 4 groups (lanes ^16, ^32)
#pragma unroll
    for (int off = 16; off < 64; off <<= 1) {
        acc.x += __shfl_xor(acc.x, off, 64);
        acc.y += __shfl_xor(acc.y, off, 64);
        acc.z += __shfl_xor(acc.z, off, 64);
        acc.w += __shfl_xor(acc.w, off, 64);
    }

    if (grp == 0) {
        size_t o = (size_t)wid * 16 + l16;
        embB[o] = acc;
        float4 ov = out[o];
        ov.x += 0.25f * acc.x;
        ov.y += 0.25f * acc.y;
        ov.z += 0.25f * acc.z;
        ov.w += 0.25f * acc.w;
        out[o] = ov;
    }
}

extern "C" void kernel_launch(void* const* d_in, const int* in_sizes, int n_in,
                              void* d_out, int out_size, void* d_ws, size_t ws_size,
                              hipStream_t stream) {
    const float* user_w = (const float*)d_in[0];
    const float* item_w = (const float*)d_in[1];
    const float* vals   = (const float*)d_in[2];
    const int*   rows   = (const int*)d_in[3];
    const int*   cols   = (const int*)d_in[4];
    const unsigned char* mask = (const unsigned char*)d_in[5];

    const int n_user = in_sizes[0] / DIM;
    const int n_item = in_sizes[1] / DIM;
    const int nnz    = in_sizes[2];
    const int n_nodes = n_user + n_item;
    const int n_elems = n_nodes * DIM;

    // ---- workspace layout ----
    char* ws = (char*)d_ws;
    size_t off = 0;
    auto alloc = [&](size_t bytes) {
        void* p = ws + off;
        off = (off + bytes + 255) & ~(size_t)255;
        return p;
    };
    int*   counts  = (int*)alloc((size_t)(n_nodes + 1) * 4);
    int*   rowptr  = (int*)alloc((size_t)(n_nodes + 1) * 4);
    int*   cursor  = (int*)alloc((size_t)(n_nodes + 1) * 4);
    int*   bsums   = (int*)alloc(SCAN_B * 4);
    int*   flag    = (int*)alloc(256);
    int2*  edges   = (int2*)alloc((size_t)nnz * 8);
    float* embA    = (float*)alloc((size_t)n_elems * 4);
    float* embB    = (float*)alloc((size_t)n_elems * 4);
    float* outf    = (float*)d_out;

    // ---- mask dtype detect ----
    detect_mask_kernel<<<1, 256, 0, stream>>>(mask, 4096, flag);

    // ---- init emb0 + acc (float4) ----
    {
        int total_v = n_elems / 4;
        init_kernel<<<2048, 256, 0, stream>>>((const float4*)user_w,
                                              (const float4*)item_w,
                                              (float4*)embA, (float4*)outf,
                                              n_user * DIM / 4, total_v);
    }

    // ---- CSR build ----
    hipMemsetAsync(counts, 0, (size_t)(n_nodes + 1) * 4, stream);
    {
        int blocks = (nnz + 255) / 256;
        hist_kernel<<<blocks, 256, 0, stream>>>(rows, mask, flag, nnz, counts);
    }
    int n_scan = n_nodes + 1;
    int nb = (n_scan + SCAN_B - 1) / SCAN_B;
    scan1_kernel<<<nb, SCAN_B, 0, stream>>>(counts, n_scan, rowptr, bsums);
    scan2_kernel<<<1, SCAN_B, 0, stream>>>(bsums, nb);
    scan3_kernel<<<nb, SCAN_B, 0, stream>>>(rowptr, counts, bsums, n_scan,
                                            rowptr, cursor);
    {
        int blocks = (nnz + 255) / 256;
        scatter_kernel<<<blocks, 256, 0, stream>>>(rows, cols, vals, mask, flag,
                                                   nnz, cursor, edges);
    }

    // ---- 3 SpMM layers (ping-pong embA/embB), acc += 0.25*layer ----
    {
        int blocks = (n_nodes + 3) / 4;  // 4 waves (rows) per 256-thread block
        spmm_kernel<<<blocks, 256, 0, stream>>>(rowptr, edges,
                                                (const float4*)embA,
                                                (float4*)embB, (float4*)outf,
                                                n_nodes);
        spmm_kernel<<<blocks, 256, 0, stream>>>(rowptr, edges,
                                                (const float4*)embB,
                                                (float4*)embA, (float4*)outf,
                                                n_nodes);
        spmm_kernel<<<blocks, 256, 0, stream>>>(rowptr, edges,
                                                (const float4*)embA,
                                                (float4*)embB, (float4*)outf,
                                                n_nodes);
    }
}

// Round 3
// 532.654 us; speedup vs baseline: 1.7919x; 1.0553x over previous
//
#include <hip/hip_runtime.h>

#define DIM 64
#define KEEP_INV 2.0f
#define BROWS 256          // rows per bucket
#define NB_MAX 640         // supports n_nodes <= 163840
#define CHUNK 8192         // edges per bucket_scatter block chunk
#define COLMASK 0x3FFFF

// ---------------- mask dtype detector ----------------
// jax bool arrays are 1 byte/elem; if widened to int32, element e's byte is
// at 4*e (LE). Nonzero-byte density over first 4KB: bool ~50%, int32 ~12.5%.
__global__ void detect_mask_kernel(const unsigned char* __restrict__ m,
                                   int nbytes, int* __restrict__ flag) {
    __shared__ int cnt;
    if (threadIdx.x == 0) cnt = 0;
    __syncthreads();
    int c = 0;
    for (int i = threadIdx.x; i < nbytes; i += blockDim.x)
        c += (m[i] != 0) ? 1 : 0;
    atomicAdd(&cnt, c);
    __syncthreads();
    if (threadIdx.x == 0) *flag = (cnt * 16 > nbytes * 5) ? 1 : 4;
}

// ---------------- emb0 = concat(user_w, item_w); acc = 0.25*emb0 ----------
__global__ void init_kernel(const float4* __restrict__ uw,
                            const float4* __restrict__ iw,
                            float4* __restrict__ embA, float4* __restrict__ out,
                            int n_user_v, int total_v) {
    int i = blockIdx.x * blockDim.x + threadIdx.x;
    int gs = gridDim.x * blockDim.x;
    for (; i < total_v; i += gs) {
        float4 v = (i < n_user_v) ? uw[i] : iw[i - n_user_v];
        embA[i] = v;
        float4 o;
        o.x = 0.25f * v.x; o.y = 0.25f * v.y;
        o.z = 0.25f * v.z; o.w = 0.25f * v.w;
        out[i] = o;
    }
}

// ---------------- bucket histogram (LDS-aggregated) ----------------
__global__ void bucket_hist_kernel(const int* __restrict__ rows,
                                   const unsigned char* __restrict__ mask,
                                   const int* __restrict__ flag, int nnz,
                                   int nb, int* __restrict__ gbhist) {
    __shared__ int lh[NB_MAX];
    for (int i = threadIdx.x; i < nb; i += blockDim.x) lh[i] = 0;
    __syncthreads();
    int sm = *flag;
    int base = blockIdx.x * CHUNK;
    int endv = min(base + CHUNK, nnz);
    for (int i = base + threadIdx.x; i < endv; i += blockDim.x)
        if (mask[(size_t)i * sm]) atomicAdd(&lh[rows[i] >> 8], 1);
    __syncthreads();
    for (int i = threadIdx.x; i < nb; i += blockDim.x)
        if (lh[i]) atomicAdd(&gbhist[i], lh[i]);
}

// ---------------- bucket scan (1 block, 1024 threads) ----------------
__global__ void bucket_scan_kernel(const int* __restrict__ gbhist, int nb,
                                   int* __restrict__ gbptr,
                                   int* __restrict__ gbcur) {
    __shared__ int s[1024];
    int t = threadIdx.x;
    s[t] = (t < nb) ? gbhist[t] : 0;
    __syncthreads();
    for (int off = 1; off < 1024; off <<= 1) {
        int x = (t >= off) ? s[t - off] : 0;
        __syncthreads();
        s[t] += x;
        __syncthreads();
    }
    if (t <= nb) {
        int e = (t == 0) ? 0 : s[t - 1];
        gbptr[t] = e;
        if (t < nb) gbcur[t] = e;
    }
}

// ---------------- bucket scatter: LDS counting-sort by bucket, bulk flush --
__global__ void __launch_bounds__(256) bucket_scatter_kernel(
        const int* __restrict__ rows, const int* __restrict__ cols,
        const float* __restrict__ vals, const unsigned char* __restrict__ mask,
        const int* __restrict__ flag, int nnz, int nb,
        int* __restrict__ gbcur, int2* __restrict__ X) {
    __shared__ int lhist[NB_MAX];
    __shared__ int lofs[NB_MAX];
    __shared__ int lcur[NB_MAX];
    __shared__ int gofs[NB_MAX];
    __shared__ int sc[2][NB_MAX];
    __shared__ int2 lbuf[CHUNK];
    int t = threadIdx.x;
    for (int i = t; i < nb; i += 256) lhist[i] = 0;
    __syncthreads();
    int sm = *flag;
    int base = blockIdx.x * CHUNK;
    int endv = min(base + CHUNK, nnz);
    // pass 1: local bucket counts
    for (int i = base + t; i < endv; i += 256)
        if (mask[(size_t)i * sm]) atomicAdd(&lhist[rows[i] >> 8], 1);
    __syncthreads();
    // inclusive Hillis-Steele scan over NB_MAX slots (covers nb<=640: 1+..+512=1023)
    for (int i = t; i < NB_MAX; i += 256) sc[0][i] = (i < nb) ? lhist[i] : 0;
    __syncthreads();
    int src = 0;
    for (int off = 1; off < NB_MAX; off <<= 1) {
        for (int i = t; i < NB_MAX; i += 256)
            sc[src ^ 1][i] = sc[src][i] + ((i >= off) ? sc[src][i - off] : 0);
        __syncthreads();
        src ^= 1;
    }
    // exclusive offsets, global reservation
    for (int i = t; i < nb; i += 256) {
        int e = (i == 0) ? 0 : sc[src][i - 1];
        lofs[i] = e;
        lcur[i] = e;
        int c = lhist[i];
        gofs[i] = c ? atomicAdd(&gbcur[i], c) : 0;
    }
    __syncthreads();
    // pass 2: place edges into LDS grouped by bucket
    for (int i = base + t; i < endv; i += 256) {
        if (mask[(size_t)i * sm]) {
            int r = rows[i];
            int b = r >> 8;
            int p = atomicAdd(&lcur[b], 1);
            int2 e;
            e.x = (cols[i] & COLMASK) | ((r & 255) << 18);
            e.y = __float_as_int(vals[i] * KEEP_INV);
            lbuf[p] = e;
        }
    }
    __syncthreads();
    // flush: one wave per bucket, coalesced segment copies
    int wid = t >> 6, lane = t & 63, nw = 256 >> 6;
    for (int b = wid; b < nb; b += nw) {
        int n = lhist[b], s0 = lofs[b], d0 = gofs[b];
        for (int j = lane; j < n; j += 64) X[d0 + j] = lbuf[s0 + j];
    }
}

// ---------------- per-bucket counting sort by row + rowptr ----------------
__global__ void __launch_bounds__(256) bucket_sort_kernel(
        const int2* __restrict__ X, const int* __restrict__ gbptr, int n_nodes,
        int2* __restrict__ Y, int* __restrict__ rowptr) {
    __shared__ int cnt[BROWS];
    __shared__ int sc[2][BROWS];
    __shared__ int rcur[BROWS];
    int b = blockIdx.x;
    int t = threadIdx.x;
    int s0 = gbptr[b], s1 = gbptr[b + 1];
    cnt[t] = 0;
    __syncthreads();
    for (int i = s0 + t; i < s1; i += 256) atomicAdd(&cnt[X[i].x >> 18], 1);
    __syncthreads();
    sc[0][t] = cnt[t];
    __syncthreads();
    int src = 0;
    for (int off = 1; off < BROWS; off <<= 1) {
        sc[src ^ 1][t] = sc[src][t] + ((t >= off) ? sc[src][t - off] : 0);
        __syncthreads();
        src ^= 1;
    }
    int excl = (t == 0) ? 0 : sc[src][t - 1];
    rcur[t] = excl;
    int gr = b * BROWS + t;
    if (gr <= n_nodes) rowptr[gr] = s0 + excl;
    __syncthreads();
    for (int i = s0 + t; i < s1; i += 256) {
        int2 e = X[i];
        int ro = e.x >> 18;
        int p = atomicAdd(&rcur[ro], 1);
        int2 o;
        o.x = e.x & COLMASK;
        o.y = e.y;
        Y[s0 + p] = o;   // scattered 8B, but within hot 32KB segment: no amp
    }
}

// ---------------- SpMM: wave per row; 4x16-lane groups; float4 lanes -------
__global__ void __launch_bounds__(256) spmm_kernel(
        const int* __restrict__ rowptr,
        const int2* __restrict__ edges,
        const float4* __restrict__ embv,
        float4* __restrict__ embB,
        float4* __restrict__ out,
        int nrows) {
    int wid = blockIdx.x * (blockDim.x >> 6) + (threadIdx.x >> 6);
    if (wid >= nrows) return;
    int lane = threadIdx.x & 63;
    int grp = lane >> 4;
    int l16 = lane & 15;
    int start = rowptr[wid];
    int end = rowptr[wid + 1];

    float4 acc;
    acc.x = acc.y = acc.z = acc.w = 0.f;

    for (int e0 = start; e0 < end; e0 += 16) {
        int c[4];
        float v[4];
#pragma unroll
        for (int k = 0; k < 4; ++k) {
            int idx = e0 + grp + 4 * k;
            int cl = idx < end ? idx : end - 1;
            int2 p = edges[cl];
            c[k] = p.x;
            v[k] = (idx < end) ? __int_as_float(p.y) : 0.f;
        }
        float4 g[4];
#pragma unroll
        for (int k = 0; k < 4; ++k)
            g[k] = embv[(size_t)c[k] * 16 + l16];
#pragma unroll
        for (int k = 0; k < 4; ++k) {
            acc.x += v[k] * g[k].x;
            acc.y += v[k] * g[k].y;
            acc.z += v[k] * g[k].z;
            acc.w += v[k] * g[k].w;
        }
    }

#pragma unroll
    for (int off = 16; off < 64; off <<= 1) {
        acc.x += __shfl_xor(acc.x, off, 64);
        acc.y += __shfl_xor(acc.y, off, 64);
        acc.z += __shfl_xor(acc.z, off, 64);
        acc.w += __shfl_xor(acc.w, off, 64);
    }

    if (grp == 0) {
        size_t o = (size_t)wid * 16 + l16;
        embB[o] = acc;
        float4 ov = out[o];
        ov.x += 0.25f * acc.x;
        ov.y += 0.25f * acc.y;
        ov.z += 0.25f * acc.z;
        ov.w += 0.25f * acc.w;
        out[o] = ov;
    }
}

extern "C" void kernel_launch(void* const* d_in, const int* in_sizes, int n_in,
                              void* d_out, int out_size, void* d_ws, size_t ws_size,
                              hipStream_t stream) {
    const float* user_w = (const float*)d_in[0];
    const float* item_w = (const float*)d_in[1];
    const float* vals   = (const float*)d_in[2];
    const int*   rows   = (const int*)d_in[3];
    const int*   cols   = (const int*)d_in[4];
    const unsigned char* mask = (const unsigned char*)d_in[5];

    const int n_user = in_sizes[0] / DIM;
    const int n_item = in_sizes[1] / DIM;
    const int nnz    = in_sizes[2];
    const int n_nodes = n_user + n_item;
    const int n_elems = n_nodes * DIM;
    const int nb = (n_nodes + BROWS - 1) / BROWS;   // 586

    // ---- workspace layout ----
    char* ws = (char*)d_ws;
    size_t off = 0;
    auto alloc = [&](size_t bytes) {
        void* p = ws + off;
        off = (off + bytes + 255) & ~(size_t)255;
        return p;
    };
    int*   gbhist = (int*)alloc((size_t)NB_MAX * 4);
    int*   gbptr  = (int*)alloc((size_t)(NB_MAX + 1) * 4);
    int*   gbcur  = (int*)alloc((size_t)NB_MAX * 4);
    int*   flag   = (int*)alloc(256);
    int*   rowptr = (int*)alloc((size_t)(n_nodes + 1) * 4);
    int2*  X      = (int2*)alloc((size_t)nnz * 8);   // bucketed scratch; reused as embB
    int2*  Y      = (int2*)alloc((size_t)nnz * 8);   // final sorted CSR edges
    float* embA   = (float*)alloc((size_t)n_elems * 4);
    float* embB   = (float*)X;  // X dead after bucket_sort; nnz*8 == n_elems*4
    float* outf   = (float*)d_out;

    detect_mask_kernel<<<1, 256, 0, stream>>>(mask, 4096, flag);

    {
        int total_v = n_elems / 4;
        init_kernel<<<2048, 256, 0, stream>>>((const float4*)user_w,
                                              (const float4*)item_w,
                                              (float4*)embA, (float4*)outf,
                                              n_user * DIM / 4, total_v);
    }

    // ---- bucketed CSR build ----
    hipMemsetAsync(gbhist, 0, (size_t)NB_MAX * 4, stream);
    int nchunks = (nnz + CHUNK - 1) / CHUNK;
    bucket_hist_kernel<<<nchunks, 256, 0, stream>>>(rows, mask, flag, nnz, nb,
                                                    gbhist);
    bucket_scan_kernel<<<1, 1024, 0, stream>>>(gbhist, nb, gbptr, gbcur);
    bucket_scatter_kernel<<<nchunks, 256, 0, stream>>>(rows, cols, vals, mask,
                                                       flag, nnz, nb, gbcur, X);
    bucket_sort_kernel<<<nb, BROWS, 0, stream>>>(X, gbptr, n_nodes, Y, rowptr);

    // ---- 3 SpMM layers (ping-pong embA/embB=X), acc += 0.25*layer ----
    {
        int blocks = (n_nodes + 3) / 4;
        spmm_kernel<<<blocks, 256, 0, stream>>>(rowptr, Y, (const float4*)embA,
                                                (float4*)embB, (float4*)outf,
                                                n_nodes);
        spmm_kernel<<<blocks, 256, 0, stream>>>(rowptr, Y, (const float4*)embB,
                                                (float4*)embA, (float4*)outf,
                                                n_nodes);
        spmm_kernel<<<blocks, 256, 0, stream>>>(rowptr, Y, (const float4*)embA,
                                                (float4*)embB, (float4*)outf,
                                                n_nodes);
    }
}

// Round 4
// 465.081 us; speedup vs baseline: 2.0523x; 1.1453x over previous
//
#include <hip/hip_runtime.h>

#define DIM 64
#define KEEP_INV 2.0f
#define BROWS 256          // rows per bucket
#define NB_MAX 640         // supports n_nodes <= 163840
#define CHUNK 8192         // edges per bucket_scatter block chunk
#define COLMASK 0x3FFFF

// ---------------- mask dtype detector ----------------
// jax bool arrays are 1 byte/elem; if widened to int32, element e's byte is
// at 4*e (LE). Nonzero-byte density over first 4KB: bool ~50%, int32 ~12.5%.
__global__ void detect_mask_kernel(const unsigned char* __restrict__ m,
                                   int nbytes, int* __restrict__ flag) {
    __shared__ int cnt;
    if (threadIdx.x == 0) cnt = 0;
    __syncthreads();
    int c = 0;
    for (int i = threadIdx.x; i < nbytes; i += blockDim.x)
        c += (m[i] != 0) ? 1 : 0;
    atomicAdd(&cnt, c);
    __syncthreads();
    if (threadIdx.x == 0) *flag = (cnt * 16 > nbytes * 5) ? 1 : 4;
}

// ---------------- emb0 = concat(user_w, item_w); acc = 0.25*emb0 ----------
__global__ void init_kernel(const float4* __restrict__ uw,
                            const float4* __restrict__ iw,
                            float4* __restrict__ embA, float4* __restrict__ out,
                            int n_user_v, int total_v) {
    int i = blockIdx.x * blockDim.x + threadIdx.x;
    int gs = gridDim.x * blockDim.x;
    for (; i < total_v; i += gs) {
        float4 v = (i < n_user_v) ? uw[i] : iw[i - n_user_v];
        embA[i] = v;
        float4 o;
        o.x = 0.25f * v.x; o.y = 0.25f * v.y;
        o.z = 0.25f * v.z; o.w = 0.25f * v.w;
        out[i] = o;
    }
}

// ---------------- bucket histogram (LDS-aggregated) ----------------
__global__ void bucket_hist_kernel(const int* __restrict__ rows,
                                   const unsigned char* __restrict__ mask,
                                   const int* __restrict__ flag, int nnz,
                                   int nb, int* __restrict__ gbhist) {
    __shared__ int lh[NB_MAX];
    for (int i = threadIdx.x; i < nb; i += blockDim.x) lh[i] = 0;
    __syncthreads();
    int sm = *flag;
    int base = blockIdx.x * CHUNK;
    int endv = min(base + CHUNK, nnz);
    for (int i = base + threadIdx.x; i < endv; i += blockDim.x)
        if (mask[(size_t)i * sm]) atomicAdd(&lh[rows[i] >> 8], 1);
    __syncthreads();
    for (int i = threadIdx.x; i < nb; i += blockDim.x)
        if (lh[i]) atomicAdd(&gbhist[i], lh[i]);
}

// ---------------- bucket scan (1 block, 1024 threads) ----------------
__global__ void bucket_scan_kernel(const int* __restrict__ gbhist, int nb,
                                   int* __restrict__ gbptr,
                                   int* __restrict__ gbcur) {
    __shared__ int s[1024];
    int t = threadIdx.x;
    s[t] = (t < nb) ? gbhist[t] : 0;
    __syncthreads();
    for (int off = 1; off < 1024; off <<= 1) {
        int x = (t >= off) ? s[t - off] : 0;
        __syncthreads();
        s[t] += x;
        __syncthreads();
    }
    if (t <= nb) {
        int e = (t == 0) ? 0 : s[t - 1];
        gbptr[t] = e;
        if (t < nb) gbcur[t] = e;
    }
}

// ---------------- bucket scatter: direct global write, per-chunk segments --
// Each chunk reserves a contiguous global slot per bucket (one atomicAdd),
// then threads write edges straight to global at LDS-cursor positions.
// Consecutive ranks -> adjacent addresses -> L2 write-combining keeps
// amplification ~1.4x. No LDS staging buffer, no scan, no flush phase.
__global__ void __launch_bounds__(256) bucket_scatter_kernel(
        const int* __restrict__ rows, const int* __restrict__ cols,
        const float* __restrict__ vals, const unsigned char* __restrict__ mask,
        const int* __restrict__ flag, int nnz, int nb,
        int* __restrict__ gbcur, int2* __restrict__ X) {
    __shared__ int lhist[NB_MAX];
    __shared__ int lcur[NB_MAX];
    int t = threadIdx.x;
    for (int i = t; i < nb; i += 256) lhist[i] = 0;
    __syncthreads();
    int sm = *flag;
    int base = blockIdx.x * CHUNK;
    int endv = min(base + CHUNK, nnz);
    // pass 1: local bucket counts
    for (int i = base + t; i < endv; i += 256)
        if (mask[(size_t)i * sm]) atomicAdd(&lhist[rows[i] >> 8], 1);
    __syncthreads();
    // reserve global segments; lcur holds GLOBAL positions
    for (int i = t; i < nb; i += 256) {
        int c = lhist[i];
        lcur[i] = c ? atomicAdd(&gbcur[i], c) : 0;
    }
    __syncthreads();
    // pass 2: write edges directly to global
    for (int i = base + t; i < endv; i += 256) {
        if (mask[(size_t)i * sm]) {
            int r = rows[i];
            int p = atomicAdd(&lcur[r >> 8], 1);
            int2 e;
            e.x = (cols[i] & COLMASK) | ((r & 255) << 18);
            e.y = __float_as_int(vals[i] * KEEP_INV);
            X[p] = e;
        }
    }
}

// ---------------- per-bucket counting sort by row + rowptr ----------------
__global__ void __launch_bounds__(256) bucket_sort_kernel(
        const int2* __restrict__ X, const int* __restrict__ gbptr, int n_nodes,
        int2* __restrict__ Y, int* __restrict__ rowptr) {
    __shared__ int cnt[BROWS];
    __shared__ int sc[2][BROWS];
    __shared__ int rcur[BROWS];
    int b = blockIdx.x;
    int t = threadIdx.x;
    int s0 = gbptr[b], s1 = gbptr[b + 1];
    cnt[t] = 0;
    __syncthreads();
    for (int i = s0 + t; i < s1; i += 256) atomicAdd(&cnt[X[i].x >> 18], 1);
    __syncthreads();
    sc[0][t] = cnt[t];
    __syncthreads();
    int src = 0;
    for (int off = 1; off < BROWS; off <<= 1) {
        sc[src ^ 1][t] = sc[src][t] + ((t >= off) ? sc[src][t - off] : 0);
        __syncthreads();
        src ^= 1;
    }
    int excl = (t == 0) ? 0 : sc[src][t - 1];
    rcur[t] = excl;
    int gr = b * BROWS + t;
    if (gr <= n_nodes) rowptr[gr] = s0 + excl;
    __syncthreads();
    for (int i = s0 + t; i < s1; i += 256) {
        int2 e = X[i];
        int ro = e.x >> 18;
        int p = atomicAdd(&rcur[ro], 1);
        int2 o;
        o.x = e.x & COLMASK;
        o.y = e.y;
        Y[s0 + p] = o;   // scattered 8B, but within hot 32KB segment: no amp
    }
}

// ---------------- SpMM: wave per row; 4x16-lane groups; float4 lanes -------
__global__ void __launch_bounds__(256) spmm_kernel(
        const int* __restrict__ rowptr,
        const int2* __restrict__ edges,
        const float4* __restrict__ embv,
        float4* __restrict__ embB,
        float4* __restrict__ out,
        int nrows) {
    int wid = blockIdx.x * (blockDim.x >> 6) + (threadIdx.x >> 6);
    if (wid >= nrows) return;
    int lane = threadIdx.x & 63;
    int grp = lane >> 4;
    int l16 = lane & 15;
    int start = rowptr[wid];
    int end = rowptr[wid + 1];

    float4 acc;
    acc.x = acc.y = acc.z = acc.w = 0.f;

    for (int e0 = start; e0 < end; e0 += 16) {
        int c[4];
        float v[4];
#pragma unroll
        for (int k = 0; k < 4; ++k) {
            int idx = e0 + grp + 4 * k;
            int cl = idx < end ? idx : end - 1;
            int2 p = edges[cl];
            c[k] = p.x;
            v[k] = (idx < end) ? __int_as_float(p.y) : 0.f;
        }
        float4 g[4];
#pragma unroll
        for (int k = 0; k < 4; ++k)
            g[k] = embv[(size_t)c[k] * 16 + l16];
#pragma unroll
        for (int k = 0; k < 4; ++k) {
            acc.x += v[k] * g[k].x;
            acc.y += v[k] * g[k].y;
            acc.z += v[k] * g[k].z;
            acc.w += v[k] * g[k].w;
        }
    }

#pragma unroll
    for (int off = 16; off < 64; off <<= 1) {
        acc.x += __shfl_xor(acc.x, off, 64);
        acc.y += __shfl_xor(acc.y, off, 64);
        acc.z += __shfl_xor(acc.z, off, 64);
        acc.w += __shfl_xor(acc.w, off, 64);
    }

    if (grp == 0) {
        size_t o = (size_t)wid * 16 + l16;
        embB[o] = acc;
        float4 ov = out[o];
        ov.x += 0.25f * acc.x;
        ov.y += 0.25f * acc.y;
        ov.z += 0.25f * acc.z;
        ov.w += 0.25f * acc.w;
        out[o] = ov;
    }
}

extern "C" void kernel_launch(void* const* d_in, const int* in_sizes, int n_in,
                              void* d_out, int out_size, void* d_ws, size_t ws_size,
                              hipStream_t stream) {
    const float* user_w = (const float*)d_in[0];
    const float* item_w = (const float*)d_in[1];
    const float* vals   = (const float*)d_in[2];
    const int*   rows   = (const int*)d_in[3];
    const int*   cols   = (const int*)d_in[4];
    const unsigned char* mask = (const unsigned char*)d_in[5];

    const int n_user = in_sizes[0] / DIM;
    const int n_item = in_sizes[1] / DIM;
    const int nnz    = in_sizes[2];
    const int n_nodes = n_user + n_item;
    const int n_elems = n_nodes * DIM;
    const int nb = (n_nodes + BROWS - 1) / BROWS;   // 586

    // ---- workspace layout ----
    char* ws = (char*)d_ws;
    size_t off = 0;
    auto alloc = [&](size_t bytes) {
        void* p = ws + off;
        off = (off + bytes + 255) & ~(size_t)255;
        return p;
    };
    int*   gbhist = (int*)alloc((size_t)NB_MAX * 4);
    int*   gbptr  = (int*)alloc((size_t)(NB_MAX + 1) * 4);
    int*   gbcur  = (int*)alloc((size_t)NB_MAX * 4);
    int*   flag   = (int*)alloc(256);
    int*   rowptr = (int*)alloc((size_t)(n_nodes + 1) * 4);
    int2*  X      = (int2*)alloc((size_t)nnz * 8);   // bucketed scratch; reused as embB
    int2*  Y      = (int2*)alloc((size_t)nnz * 8);   // final sorted CSR edges
    float* embA   = (float*)alloc((size_t)n_elems * 4);
    float* embB   = (float*)X;  // X dead after bucket_sort; nnz*8 == n_elems*4
    float* outf   = (float*)d_out;

    detect_mask_kernel<<<1, 256, 0, stream>>>(mask, 4096, flag);

    {
        int total_v = n_elems / 4;
        init_kernel<<<2048, 256, 0, stream>>>((const float4*)user_w,
                                              (const float4*)item_w,
                                              (float4*)embA, (float4*)outf,
                                              n_user * DIM / 4, total_v);
    }

    // ---- bucketed CSR build ----
    hipMemsetAsync(gbhist, 0, (size_t)NB_MAX * 4, stream);
    int nchunks = (nnz + CHUNK - 1) / CHUNK;
    bucket_hist_kernel<<<nchunks, 256, 0, stream>>>(rows, mask, flag, nnz, nb,
                                                    gbhist);
    bucket_scan_kernel<<<1, 1024, 0, stream>>>(gbhist, nb, gbptr, gbcur);
    bucket_scatter_kernel<<<nchunks, 256, 0, stream>>>(rows, cols, vals, mask,
                                                       flag, nnz, nb, gbcur, X);
    bucket_sort_kernel<<<nb, BROWS, 0, stream>>>(X, gbptr, n_nodes, Y, rowptr);

    // ---- 3 SpMM layers (ping-pong embA/embB=X), acc += 0.25*layer ----
    {
        int blocks = (n_nodes + 3) / 4;
        spmm_kernel<<<blocks, 256, 0, stream>>>(rowptr, Y, (const float4*)embA,
                                                (float4*)embB, (float4*)outf,
                                                n_nodes);
        spmm_kernel<<<blocks, 256, 0, stream>>>(rowptr, Y, (const float4*)embB,
                                                (float4*)embA, (float4*)outf,
                                                n_nodes);
        spmm_kernel<<<blocks, 256, 0, stream>>>(rowptr, Y, (const float4*)embA,
                                                (float4*)embB, (float4*)outf,
                                                n_nodes);
    }
}

// Round 5
// 407.744 us; speedup vs baseline: 2.3408x; 1.1406x over previous
//
#include <hip/hip_runtime.h>

#define DIM 64
#define KEEP_INV 2.0f
#define BROWS 256          // rows per bucket
#define NB_MAX 640         // supports n_nodes <= 163840
#define CHUNK 4096         // edges per scatter/hist block chunk
#define SC_T 512           // scatter threads per block
#define EPT 8              // edges per thread (CHUNK / SC_T)
#define COLMASK 0x3FFFF

// ---------------- mask dtype detector ----------------
// jax bool arrays are 1 byte/elem; if widened to int32, element e's byte is
// at 4*e (LE). Nonzero-byte density over first 4KB: bool ~50%, int32 ~12.5%.
__global__ void detect_mask_kernel(const unsigned char* __restrict__ m,
                                   int nbytes, int* __restrict__ flag) {
    __shared__ int cnt;
    if (threadIdx.x == 0) cnt = 0;
    __syncthreads();
    int c = 0;
    for (int i = threadIdx.x; i < nbytes; i += blockDim.x)
        c += (m[i] != 0) ? 1 : 0;
    atomicAdd(&cnt, c);
    __syncthreads();
    if (threadIdx.x == 0) *flag = (cnt * 16 > nbytes * 5) ? 1 : 4;
}

// ---------------- emb0 = concat(user_w, item_w); acc = 0.25*emb0 ----------
__global__ void init_kernel(const float4* __restrict__ uw,
                            const float4* __restrict__ iw,
                            float4* __restrict__ embA, float4* __restrict__ out,
                            int n_user_v, int total_v) {
    int i = blockIdx.x * blockDim.x + threadIdx.x;
    int gs = gridDim.x * blockDim.x;
    for (; i < total_v; i += gs) {
        float4 v = (i < n_user_v) ? uw[i] : iw[i - n_user_v];
        embA[i] = v;
        float4 o;
        o.x = 0.25f * v.x; o.y = 0.25f * v.y;
        o.z = 0.25f * v.z; o.w = 0.25f * v.w;
        out[i] = o;
    }
}

// ---- helper: load 8 edges' keep-mask as a bitmask (vector path) ----------
__device__ inline int load_keep8(const unsigned char* mask, int e0, int sm) {
    int keep = 0;
    if (sm == 1) {
        uint2 mv = *(const uint2*)(mask + e0);
#pragma unroll
        for (int j = 0; j < 4; ++j) {
            if ((mv.x >> (8 * j)) & 0xFF) keep |= 1 << j;
            if ((mv.y >> (8 * j)) & 0xFF) keep |= 1 << (4 + j);
        }
    } else {
        const int4* mp = (const int4*)((const int*)mask + e0);
        int4 m0 = mp[0], m1 = mp[1];
        if (m0.x) keep |= 1;  if (m0.y) keep |= 2;
        if (m0.z) keep |= 4;  if (m0.w) keep |= 8;
        if (m1.x) keep |= 16; if (m1.y) keep |= 32;
        if (m1.z) keep |= 64; if (m1.w) keep |= 128;
    }
    return keep;
}

// ---------------- bucket histogram (vectorized, LDS-aggregated) -----------
__global__ void __launch_bounds__(SC_T, 8) bucket_hist_kernel(
        const int* __restrict__ rows, const unsigned char* __restrict__ mask,
        const int* __restrict__ flag, int nnz, int nb,
        int* __restrict__ gbhist) {
    __shared__ int lh[NB_MAX];
    int t = threadIdx.x;
    for (int i = t; i < nb; i += SC_T) lh[i] = 0;
    __syncthreads();
    int sm = *flag;
    int e0 = blockIdx.x * CHUNK + t * EPT;
    if (e0 + EPT <= nnz) {
        const int4* rp = (const int4*)(rows + e0);
        int4 r0 = rp[0], r1 = rp[1];
        int r[EPT] = {r0.x, r0.y, r0.z, r0.w, r1.x, r1.y, r1.z, r1.w};
        int keep = load_keep8(mask, e0, sm);
#pragma unroll
        for (int j = 0; j < EPT; ++j)
            if ((keep >> j) & 1) atomicAdd(&lh[r[j] >> 8], 1);
    } else {
        for (int j = 0; j < EPT; ++j) {
            int idx = e0 + j;
            if (idx < nnz && mask[(size_t)idx * sm])
                atomicAdd(&lh[rows[idx] >> 8], 1);
        }
    }
    __syncthreads();
    for (int i = t; i < nb; i += SC_T)
        if (lh[i]) atomicAdd(&gbhist[i], lh[i]);
}

// ---------------- bucket scan (1 block, 1024 threads) ----------------
__global__ void bucket_scan_kernel(const int* __restrict__ gbhist, int nb,
                                   int* __restrict__ gbptr,
                                   int* __restrict__ gbcur) {
    __shared__ int s[1024];
    int t = threadIdx.x;
    s[t] = (t < nb) ? gbhist[t] : 0;
    __syncthreads();
    for (int off = 1; off < 1024; off <<= 1) {
        int x = (t >= off) ? s[t - off] : 0;
        __syncthreads();
        s[t] += x;
        __syncthreads();
    }
    if (t <= nb) {
        int e = (t == 0) ? 0 : s[t - 1];
        gbptr[t] = e;
        if (t < nb) gbcur[t] = e;
    }
}

// ---------------- bucket scatter: register-staged, direct global write ----
// Each thread owns 8 contiguous edges, loaded ONCE via int4/float4/uint2.
// Pass 1: LDS bucket histogram. Reserve: one global atomicAdd per bucket.
// Pass 2: emit from registers to global at LDS-cursor positions (segments
// per (chunk,bucket) are contiguous -> low write amplification).
__global__ void __launch_bounds__(SC_T, 8) bucket_scatter_kernel(
        const int* __restrict__ rows, const int* __restrict__ cols,
        const float* __restrict__ vals, const unsigned char* __restrict__ mask,
        const int* __restrict__ flag, int nnz, int nb,
        int* __restrict__ gbcur, int2* __restrict__ X) {
    __shared__ int lhist[NB_MAX];
    __shared__ int lcur[NB_MAX];
    int t = threadIdx.x;
    for (int i = t; i < nb; i += SC_T) lhist[i] = 0;
    __syncthreads();
    int sm = *flag;
    int e0 = blockIdx.x * CHUNK + t * EPT;

    int r[EPT], c[EPT];
    float v[EPT];
    int keep = 0;
    if (e0 + EPT <= nnz) {
        const int4* rp = (const int4*)(rows + e0);
        int4 a0 = rp[0], a1 = rp[1];
        r[0] = a0.x; r[1] = a0.y; r[2] = a0.z; r[3] = a0.w;
        r[4] = a1.x; r[5] = a1.y; r[6] = a1.z; r[7] = a1.w;
        const int4* cp = (const int4*)(cols + e0);
        int4 b0 = cp[0], b1 = cp[1];
        c[0] = b0.x; c[1] = b0.y; c[2] = b0.z; c[3] = b0.w;
        c[4] = b1.x; c[5] = b1.y; c[6] = b1.z; c[7] = b1.w;
        const float4* vp = (const float4*)(vals + e0);
        float4 f0 = vp[0], f1 = vp[1];
        v[0] = f0.x; v[1] = f0.y; v[2] = f0.z; v[3] = f0.w;
        v[4] = f1.x; v[5] = f1.y; v[6] = f1.z; v[7] = f1.w;
        keep = load_keep8(mask, e0, sm);
    } else {
        for (int j = 0; j < EPT; ++j) {
            int idx = e0 + j;
            if (idx < nnz) {
                r[j] = rows[idx];
                c[j] = cols[idx];
                v[j] = vals[idx];
                if (mask[(size_t)idx * sm]) keep |= 1 << j;
            }
        }
    }

    // pass 1: local bucket counts
#pragma unroll
    for (int j = 0; j < EPT; ++j)
        if ((keep >> j) & 1) atomicAdd(&lhist[r[j] >> 8], 1);
    __syncthreads();
    // reserve global segments; lcur holds GLOBAL positions
    for (int i = t; i < nb; i += SC_T) {
        int cc = lhist[i];
        lcur[i] = cc ? atomicAdd(&gbcur[i], cc) : 0;
    }
    __syncthreads();
    // pass 2: emit from registers
#pragma unroll
    for (int j = 0; j < EPT; ++j) {
        if ((keep >> j) & 1) {
            int p = atomicAdd(&lcur[r[j] >> 8], 1);
            int2 e;
            e.x = (c[j] & COLMASK) | ((r[j] & 255) << 18);
            e.y = __float_as_int(v[j] * KEEP_INV);
            X[p] = e;
        }
    }
}

// ---------------- per-bucket counting sort by row + rowptr ----------------
__global__ void __launch_bounds__(256) bucket_sort_kernel(
        const int2* __restrict__ X, const int* __restrict__ gbptr, int n_nodes,
        int2* __restrict__ Y, int* __restrict__ rowptr) {
    __shared__ int cnt[BROWS];
    __shared__ int sc[2][BROWS];
    __shared__ int rcur[BROWS];
    int b = blockIdx.x;
    int t = threadIdx.x;
    int s0 = gbptr[b], s1 = gbptr[b + 1];
    cnt[t] = 0;
    __syncthreads();
    for (int i = s0 + t; i < s1; i += 256) atomicAdd(&cnt[X[i].x >> 18], 1);
    __syncthreads();
    sc[0][t] = cnt[t];
    __syncthreads();
    int src = 0;
    for (int off = 1; off < BROWS; off <<= 1) {
        sc[src ^ 1][t] = sc[src][t] + ((t >= off) ? sc[src][t - off] : 0);
        __syncthreads();
        src ^= 1;
    }
    int excl = (t == 0) ? 0 : sc[src][t - 1];
    rcur[t] = excl;
    int gr = b * BROWS + t;
    if (gr <= n_nodes) rowptr[gr] = s0 + excl;
    __syncthreads();
    for (int i = s0 + t; i < s1; i += 256) {
        int2 e = X[i];
        int ro = e.x >> 18;
        int p = atomicAdd(&rcur[ro], 1);
        int2 o;
        o.x = e.x & COLMASK;
        o.y = e.y;
        Y[s0 + p] = o;   // scattered 8B, but within hot 32KB segment: no amp
    }
}

// ---------------- SpMM: wave per row; 4x16-lane groups; float4 lanes -------
__global__ void __launch_bounds__(256) spmm_kernel(
        const int* __restrict__ rowptr,
        const int2* __restrict__ edges,
        const float4* __restrict__ embv,
        float4* __restrict__ embB,
        float4* __restrict__ out,
        int nrows) {
    int wid = blockIdx.x * (blockDim.x >> 6) + (threadIdx.x >> 6);
    if (wid >= nrows) return;
    int lane = threadIdx.x & 63;
    int grp = lane >> 4;
    int l16 = lane & 15;
    int start = rowptr[wid];
    int end = rowptr[wid + 1];

    float4 acc;
    acc.x = acc.y = acc.z = acc.w = 0.f;

    for (int e0 = start; e0 < end; e0 += 16) {
        int c[4];
        float v[4];
#pragma unroll
        for (int k = 0; k < 4; ++k) {
            int idx = e0 + grp + 4 * k;
            int cl = idx < end ? idx : end - 1;
            int2 p = edges[cl];
            c[k] = p.x;
            v[k] = (idx < end) ? __int_as_float(p.y) : 0.f;
        }
        float4 g[4];
#pragma unroll
        for (int k = 0; k < 4; ++k)
            g[k] = embv[(size_t)c[k] * 16 + l16];
#pragma unroll
        for (int k = 0; k < 4; ++k) {
            acc.x += v[k] * g[k].x;
            acc.y += v[k] * g[k].y;
            acc.z += v[k] * g[k].z;
            acc.w += v[k] * g[k].w;
        }
    }

#pragma unroll
    for (int off = 16; off < 64; off <<= 1) {
        acc.x += __shfl_xor(acc.x, off, 64);
        acc.y += __shfl_xor(acc.y, off, 64);
        acc.z += __shfl_xor(acc.z, off, 64);
        acc.w += __shfl_xor(acc.w, off, 64);
    }

    if (grp == 0) {
        size_t o = (size_t)wid * 16 + l16;
        embB[o] = acc;
        float4 ov = out[o];
        ov.x += 0.25f * acc.x;
        ov.y += 0.25f * acc.y;
        ov.z += 0.25f * acc.z;
        ov.w += 0.25f * acc.w;
        out[o] = ov;
    }
}

extern "C" void kernel_launch(void* const* d_in, const int* in_sizes, int n_in,
                              void* d_out, int out_size, void* d_ws, size_t ws_size,
                              hipStream_t stream) {
    const float* user_w = (const float*)d_in[0];
    const float* item_w = (const float*)d_in[1];
    const float* vals   = (const float*)d_in[2];
    const int*   rows   = (const int*)d_in[3];
    const int*   cols   = (const int*)d_in[4];
    const unsigned char* mask = (const unsigned char*)d_in[5];

    const int n_user = in_sizes[0] / DIM;
    const int n_item = in_sizes[1] / DIM;
    const int nnz    = in_sizes[2];
    const int n_nodes = n_user + n_item;
    const int n_elems = n_nodes * DIM;
    const int nb = (n_nodes + BROWS - 1) / BROWS;   // 586

    // ---- workspace layout ----
    char* ws = (char*)d_ws;
    size_t off = 0;
    auto alloc = [&](size_t bytes) {
        void* p = ws + off;
        off = (off + bytes + 255) & ~(size_t)255;
        return p;
    };
    int*   gbhist = (int*)alloc((size_t)NB_MAX * 4);
    int*   gbptr  = (int*)alloc((size_t)(NB_MAX + 1) * 4);
    int*   gbcur  = (int*)alloc((size_t)NB_MAX * 4);
    int*   flag   = (int*)alloc(256);
    int*   rowptr = (int*)alloc((size_t)(n_nodes + 1) * 4);
    int2*  X      = (int2*)alloc((size_t)nnz * 8);   // bucketed scratch; reused as embB
    int2*  Y      = (int2*)alloc((size_t)nnz * 8);   // final sorted CSR edges
    float* embA   = (float*)alloc((size_t)n_elems * 4);
    float* embB   = (float*)X;  // X dead after bucket_sort; nnz*8 == n_elems*4
    float* outf   = (float*)d_out;

    detect_mask_kernel<<<1, 256, 0, stream>>>(mask, 4096, flag);

    {
        int total_v = n_elems / 4;
        init_kernel<<<2048, 256, 0, stream>>>((const float4*)user_w,
                                              (const float4*)item_w,
                                              (float4*)embA, (float4*)outf,
                                              n_user * DIM / 4, total_v);
    }

    // ---- bucketed CSR build ----
    hipMemsetAsync(gbhist, 0, (size_t)NB_MAX * 4, stream);
    int nchunks = (nnz + CHUNK - 1) / CHUNK;
    bucket_hist_kernel<<<nchunks, SC_T, 0, stream>>>(rows, mask, flag, nnz, nb,
                                                     gbhist);
    bucket_scan_kernel<<<1, 1024, 0, stream>>>(gbhist, nb, gbptr, gbcur);
    bucket_scatter_kernel<<<nchunks, SC_T, 0, stream>>>(rows, cols, vals, mask,
                                                        flag, nnz, nb, gbcur, X);
    bucket_sort_kernel<<<nb, BROWS, 0, stream>>>(X, gbptr, n_nodes, Y, rowptr);

    // ---- 3 SpMM layers (ping-pong embA/embB=X), acc += 0.25*layer ----
    {
        int blocks = (n_nodes + 3) / 4;
        spmm_kernel<<<blocks, 256, 0, stream>>>(rowptr, Y, (const float4*)embA,
                                                (float4*)embB, (float4*)outf,
                                                n_nodes);
        spmm_kernel<<<blocks, 256, 0, stream>>>(rowptr, Y, (const float4*)embB,
                                                (float4*)embA, (float4*)outf,
                                                n_nodes);
        spmm_kernel<<<blocks, 256, 0, stream>>>(rowptr, Y, (const float4*)embA,
                                                (float4*)embB, (float4*)outf,
                                                n_nodes);
    }
}

// Round 6
// 321.164 us; speedup vs baseline: 2.9719x; 1.2696x over previous
//
#include <hip/hip_runtime.h>
#include <hip/hip_fp16.h>

#define DIM 64
#define KEEP_INV 2.0f
#define BROWS 256          // rows per bucket
#define NB_MAX 640         // supports n_nodes <= 163840
#define CHUNK 4096         // edges per scatter/hist block chunk
#define SC_T 512           // scatter threads per block
#define EPT 8              // edges per thread (CHUNK / SC_T)
#define COLMASK 0x3FFFF

// ---------------- mask dtype detector ----------------
// jax bool arrays are 1 byte/elem; if widened to int32, element e's byte is
// at 4*e (LE). Nonzero-byte density over first 4KB: bool ~50%, int32 ~12.5%.
__global__ void detect_mask_kernel(const unsigned char* __restrict__ m,
                                   int nbytes, int* __restrict__ flag) {
    __shared__ int cnt;
    if (threadIdx.x == 0) cnt = 0;
    __syncthreads();
    int c = 0;
    for (int i = threadIdx.x; i < nbytes; i += blockDim.x)
        c += (m[i] != 0) ? 1 : 0;
    atomicAdd(&cnt, c);
    __syncthreads();
    if (threadIdx.x == 0) *flag = (cnt * 16 > nbytes * 5) ? 1 : 4;
}

// ------- emb0 f16 table = concat(user_w, item_w); out = 0.25*emb0 (f32) ----
// thread i owns 4 elements: float4 in, uint2 (4 halves) to table, float4 out.
__global__ void init_kernel(const float4* __restrict__ uw,
                            const float4* __restrict__ iw,
                            uint2* __restrict__ embA16,
                            float4* __restrict__ out,
                            int n_user_v, int total_v) {
    int i = blockIdx.x * blockDim.x + threadIdx.x;
    int gs = gridDim.x * blockDim.x;
    for (; i < total_v; i += gs) {
        float4 v = (i < n_user_v) ? uw[i] : iw[i - n_user_v];
        __half2 h0 = __float22half2_rn(make_float2(v.x, v.y));
        __half2 h1 = __float22half2_rn(make_float2(v.z, v.w));
        uint2 pk;
        pk.x = *(unsigned int*)&h0;
        pk.y = *(unsigned int*)&h1;
        embA16[i] = pk;
        float4 o;
        o.x = 0.25f * v.x; o.y = 0.25f * v.y;
        o.z = 0.25f * v.z; o.w = 0.25f * v.w;
        out[i] = o;
    }
}

// ---- helper: load 8 edges' keep-mask as a bitmask (vector path) ----------
__device__ inline int load_keep8(const unsigned char* mask, int e0, int sm) {
    int keep = 0;
    if (sm == 1) {
        uint2 mv = *(const uint2*)(mask + e0);
#pragma unroll
        for (int j = 0; j < 4; ++j) {
            if ((mv.x >> (8 * j)) & 0xFF) keep |= 1 << j;
            if ((mv.y >> (8 * j)) & 0xFF) keep |= 1 << (4 + j);
        }
    } else {
        const int4* mp = (const int4*)((const int*)mask + e0);
        int4 m0 = mp[0], m1 = mp[1];
        if (m0.x) keep |= 1;  if (m0.y) keep |= 2;
        if (m0.z) keep |= 4;  if (m0.w) keep |= 8;
        if (m1.x) keep |= 16; if (m1.y) keep |= 32;
        if (m1.z) keep |= 64; if (m1.w) keep |= 128;
    }
    return keep;
}

// ---------------- bucket histogram (vectorized, LDS-aggregated) -----------
__global__ void __launch_bounds__(SC_T, 8) bucket_hist_kernel(
        const int* __restrict__ rows, const unsigned char* __restrict__ mask,
        const int* __restrict__ flag, int nnz, int nb,
        int* __restrict__ gbhist) {
    __shared__ int lh[NB_MAX];
    int t = threadIdx.x;
    for (int i = t; i < nb; i += SC_T) lh[i] = 0;
    __syncthreads();
    int sm = *flag;
    int e0 = blockIdx.x * CHUNK + t * EPT;
    if (e0 + EPT <= nnz) {
        const int4* rp = (const int4*)(rows + e0);
        int4 r0 = rp[0], r1 = rp[1];
        int r[EPT] = {r0.x, r0.y, r0.z, r0.w, r1.x, r1.y, r1.z, r1.w};
        int keep = load_keep8(mask, e0, sm);
#pragma unroll
        for (int j = 0; j < EPT; ++j)
            if ((keep >> j) & 1) atomicAdd(&lh[r[j] >> 8], 1);
    } else {
        for (int j = 0; j < EPT; ++j) {
            int idx = e0 + j;
            if (idx < nnz && mask[(size_t)idx * sm])
                atomicAdd(&lh[rows[idx] >> 8], 1);
        }
    }
    __syncthreads();
    for (int i = t; i < nb; i += SC_T)
        if (lh[i]) atomicAdd(&gbhist[i], lh[i]);
}

// ---------------- bucket scan (1 block, 1024 threads) ----------------
__global__ void bucket_scan_kernel(const int* __restrict__ gbhist, int nb,
                                   int* __restrict__ gbptr,
                                   int* __restrict__ gbcur) {
    __shared__ int s[1024];
    int t = threadIdx.x;
    s[t] = (t < nb) ? gbhist[t] : 0;
    __syncthreads();
    for (int off = 1; off < 1024; off <<= 1) {
        int x = (t >= off) ? s[t - off] : 0;
        __syncthreads();
        s[t] += x;
        __syncthreads();
    }
    if (t <= nb) {
        int e = (t == 0) ? 0 : s[t - 1];
        gbptr[t] = e;
        if (t < nb) gbcur[t] = e;
    }
}

// ---------------- bucket scatter: register-staged, direct global write ----
__global__ void __launch_bounds__(SC_T, 8) bucket_scatter_kernel(
        const int* __restrict__ rows, const int* __restrict__ cols,
        const float* __restrict__ vals, const unsigned char* __restrict__ mask,
        const int* __restrict__ flag, int nnz, int nb,
        int* __restrict__ gbcur, int2* __restrict__ X) {
    __shared__ int lhist[NB_MAX];
    __shared__ int lcur[NB_MAX];
    int t = threadIdx.x;
    for (int i = t; i < nb; i += SC_T) lhist[i] = 0;
    __syncthreads();
    int sm = *flag;
    int e0 = blockIdx.x * CHUNK + t * EPT;

    int r[EPT], c[EPT];
    float v[EPT];
    int keep = 0;
    if (e0 + EPT <= nnz) {
        const int4* rp = (const int4*)(rows + e0);
        int4 a0 = rp[0], a1 = rp[1];
        r[0] = a0.x; r[1] = a0.y; r[2] = a0.z; r[3] = a0.w;
        r[4] = a1.x; r[5] = a1.y; r[6] = a1.z; r[7] = a1.w;
        const int4* cp = (const int4*)(cols + e0);
        int4 b0 = cp[0], b1 = cp[1];
        c[0] = b0.x; c[1] = b0.y; c[2] = b0.z; c[3] = b0.w;
        c[4] = b1.x; c[5] = b1.y; c[6] = b1.z; c[7] = b1.w;
        const float4* vp = (const float4*)(vals + e0);
        float4 f0 = vp[0], f1 = vp[1];
        v[0] = f0.x; v[1] = f0.y; v[2] = f0.z; v[3] = f0.w;
        v[4] = f1.x; v[5] = f1.y; v[6] = f1.z; v[7] = f1.w;
        keep = load_keep8(mask, e0, sm);
    } else {
        for (int j = 0; j < EPT; ++j) {
            int idx = e0 + j;
            if (idx < nnz) {
                r[j] = rows[idx];
                c[j] = cols[idx];
                v[j] = vals[idx];
                if (mask[(size_t)idx * sm]) keep |= 1 << j;
            }
        }
    }

#pragma unroll
    for (int j = 0; j < EPT; ++j)
        if ((keep >> j) & 1) atomicAdd(&lhist[r[j] >> 8], 1);
    __syncthreads();
    for (int i = t; i < nb; i += SC_T) {
        int cc = lhist[i];
        lcur[i] = cc ? atomicAdd(&gbcur[i], cc) : 0;
    }
    __syncthreads();
#pragma unroll
    for (int j = 0; j < EPT; ++j) {
        if ((keep >> j) & 1) {
            int p = atomicAdd(&lcur[r[j] >> 8], 1);
            int2 e;
            e.x = (c[j] & COLMASK) | ((r[j] & 255) << 18);
            e.y = __float_as_int(v[j] * KEEP_INV);
            X[p] = e;
        }
    }
}

// ---------------- per-bucket counting sort by row + rowptr ----------------
__global__ void __launch_bounds__(256) bucket_sort_kernel(
        const int2* __restrict__ X, const int* __restrict__ gbptr, int n_nodes,
        int2* __restrict__ Y, int* __restrict__ rowptr) {
    __shared__ int cnt[BROWS];
    __shared__ int sc[2][BROWS];
    __shared__ int rcur[BROWS];
    int b = blockIdx.x;
    int t = threadIdx.x;
    int s0 = gbptr[b], s1 = gbptr[b + 1];
    cnt[t] = 0;
    __syncthreads();
    for (int i = s0 + t; i < s1; i += 256) atomicAdd(&cnt[X[i].x >> 18], 1);
    __syncthreads();
    sc[0][t] = cnt[t];
    __syncthreads();
    int src = 0;
    for (int off = 1; off < BROWS; off <<= 1) {
        sc[src ^ 1][t] = sc[src][t] + ((t >= off) ? sc[src][t - off] : 0);
        __syncthreads();
        src ^= 1;
    }
    int excl = (t == 0) ? 0 : sc[src][t - 1];
    rcur[t] = excl;
    int gr = b * BROWS + t;
    if (gr <= n_nodes) rowptr[gr] = s0 + excl;
    __syncthreads();
    for (int i = s0 + t; i < s1; i += 256) {
        int2 e = X[i];
        int ro = e.x >> 18;
        int p = atomicAdd(&rcur[ro], 1);
        int2 o;
        o.x = e.x & COLMASK;
        o.y = e.y;
        Y[s0 + p] = o;   // scattered 8B, but within hot 32KB segment: no amp
    }
}

// --------- SpMM (f16 table): wave per row; 4x16-lane groups; uint2 lanes ---
// Gather 128B/row as 16 lanes x 8B (4 halves), convert to f32, accumulate
// f32, write next-layer f16 row + f32 out RMW.
__global__ void __launch_bounds__(256) spmm_kernel(
        const int* __restrict__ rowptr,
        const int2* __restrict__ edges,
        const uint2* __restrict__ embv16,   // [n_nodes * 16] uint2 (4 halves)
        uint2* __restrict__ embB16,
        float4* __restrict__ out,
        int nrows) {
    int wid = blockIdx.x * (blockDim.x >> 6) + (threadIdx.x >> 6);
    if (wid >= nrows) return;
    int lane = threadIdx.x & 63;
    int grp = lane >> 4;
    int l16 = lane & 15;
    int start = rowptr[wid];
    int end = rowptr[wid + 1];

    float4 acc;
    acc.x = acc.y = acc.z = acc.w = 0.f;

    for (int e0 = start; e0 < end; e0 += 16) {
        int c[4];
        float v[4];
#pragma unroll
        for (int k = 0; k < 4; ++k) {
            int idx = e0 + grp + 4 * k;
            int cl = idx < end ? idx : end - 1;
            int2 p = edges[cl];
            c[k] = p.x;
            v[k] = (idx < end) ? __int_as_float(p.y) : 0.f;
        }
        uint2 g[4];
#pragma unroll
        for (int k = 0; k < 4; ++k)
            g[k] = embv16[(size_t)c[k] * 16 + l16];
#pragma unroll
        for (int k = 0; k < 4; ++k) {
            float2 f01 = __half22float2(*(const __half2*)&g[k].x);
            float2 f23 = __half22float2(*(const __half2*)&g[k].y);
            acc.x += v[k] * f01.x;
            acc.y += v[k] * f01.y;
            acc.z += v[k] * f23.x;
            acc.w += v[k] * f23.y;
        }
    }

#pragma unroll
    for (int off = 16; off < 64; off <<= 1) {
        acc.x += __shfl_xor(acc.x, off, 64);
        acc.y += __shfl_xor(acc.y, off, 64);
        acc.z += __shfl_xor(acc.z, off, 64);
        acc.w += __shfl_xor(acc.w, off, 64);
    }

    if (grp == 0) {
        size_t o = (size_t)wid * 16 + l16;
        __half2 h0 = __float22half2_rn(make_float2(acc.x, acc.y));
        __half2 h1 = __float22half2_rn(make_float2(acc.z, acc.w));
        uint2 pk;
        pk.x = *(unsigned int*)&h0;
        pk.y = *(unsigned int*)&h1;
        embB16[o] = pk;
        float4 ov = out[o];
        ov.x += 0.25f * acc.x;
        ov.y += 0.25f * acc.y;
        ov.z += 0.25f * acc.z;
        ov.w += 0.25f * acc.w;
        out[o] = ov;
    }
}

extern "C" void kernel_launch(void* const* d_in, const int* in_sizes, int n_in,
                              void* d_out, int out_size, void* d_ws, size_t ws_size,
                              hipStream_t stream) {
    const float* user_w = (const float*)d_in[0];
    const float* item_w = (const float*)d_in[1];
    const float* vals   = (const float*)d_in[2];
    const int*   rows   = (const int*)d_in[3];
    const int*   cols   = (const int*)d_in[4];
    const unsigned char* mask = (const unsigned char*)d_in[5];

    const int n_user = in_sizes[0] / DIM;
    const int n_item = in_sizes[1] / DIM;
    const int nnz    = in_sizes[2];
    const int n_nodes = n_user + n_item;
    const int n_elems = n_nodes * DIM;
    const int nb = (n_nodes + BROWS - 1) / BROWS;   // 586

    // ---- workspace layout ----
    char* ws = (char*)d_ws;
    size_t off = 0;
    auto alloc = [&](size_t bytes) {
        void* p = ws + off;
        off = (off + bytes + 255) & ~(size_t)255;
        return p;
    };
    int*   gbhist = (int*)alloc((size_t)NB_MAX * 4);
    int*   gbptr  = (int*)alloc((size_t)(NB_MAX + 1) * 4);
    int*   gbcur  = (int*)alloc((size_t)NB_MAX * 4);
    int*   flag   = (int*)alloc(256);
    int*   rowptr = (int*)alloc((size_t)(n_nodes + 1) * 4);
    int2*  X      = (int2*)alloc((size_t)nnz * 8);   // bucketed scratch; reused as embB16
    int2*  Y      = (int2*)alloc((size_t)nnz * 8);   // final sorted CSR edges
    uint2* embA16 = (uint2*)alloc((size_t)n_nodes * 16 * 8);  // f16 table 19.2MB
    uint2* embB16 = (uint2*)X;  // X dead after bucket_sort; 19.2MB fits in 38.4MB
    float* outf   = (float*)d_out;

    detect_mask_kernel<<<1, 256, 0, stream>>>(mask, 4096, flag);

    {
        int total_v = n_elems / 4;
        init_kernel<<<2048, 256, 0, stream>>>((const float4*)user_w,
                                              (const float4*)item_w,
                                              embA16, (float4*)outf,
                                              n_user * DIM / 4, total_v);
    }

    // ---- bucketed CSR build ----
    hipMemsetAsync(gbhist, 0, (size_t)NB_MAX * 4, stream);
    int nchunks = (nnz + CHUNK - 1) / CHUNK;
    bucket_hist_kernel<<<nchunks, SC_T, 0, stream>>>(rows, mask, flag, nnz, nb,
                                                     gbhist);
    bucket_scan_kernel<<<1, 1024, 0, stream>>>(gbhist, nb, gbptr, gbcur);
    bucket_scatter_kernel<<<nchunks, SC_T, 0, stream>>>(rows, cols, vals, mask,
                                                        flag, nnz, nb, gbcur, X);
    bucket_sort_kernel<<<nb, BROWS, 0, stream>>>(X, gbptr, n_nodes, Y, rowptr);

    // ---- 3 SpMM layers (ping-pong embA16/embB16=X), acc += 0.25*layer ----
    {
        int blocks = (n_nodes + 3) / 4;
        spmm_kernel<<<blocks, 256, 0, stream>>>(rowptr, Y, embA16, embB16,
                                                (float4*)outf, n_nodes);
        spmm_kernel<<<blocks, 256, 0, stream>>>(rowptr, Y, embB16, embA16,
                                                (float4*)outf, n_nodes);
        spmm_kernel<<<blocks, 256, 0, stream>>>(rowptr, Y, embA16, embB16,
                                                (float4*)outf, n_nodes);
    }
}